// Round 6
// baseline (2345.174 us; speedup 1.0000x reference)
//
#include <hip/hip_runtime.h>
#include <cstdint>

// SelfMatchingLayer: B=32, L=512, H=256, fp32.
// R6: R4/R5 failed with IDENTICAL absmax 4.05e-2 -> deterministic shared
// bug, not carry quantization. Found: bhh fold into k6 is wrong for the
// n-gate: reference has n = tanh(inn + bih_n + r*((Whh h)_n + bhh_n)) --
// bhh_n sits INSIDE the r-multiply. Fix: k6 folds bhh only for r/z blocks
// (cols < 512); k7 loads bhh_n per lane (16 vals) and computes
// tanh(gN + r*(Cn + bhh_n)). fp32 carry kept from R5.

#define LL 512
#define HH 256

typedef _Float16 f16x8 __attribute__((ext_vector_type(8)));
typedef _Float16 f16x4 __attribute__((ext_vector_type(4)));
typedef float    f32x4 __attribute__((ext_vector_type(4)));

__device__ __forceinline__ float exp2f_fast(float x){
#if defined(__HIP_DEVICE_COMPILE__)
  return __builtin_amdgcn_exp2f(x);
#else
  return exp2f(x);
#endif
}
__device__ __forceinline__ float rcpf_fast(float x){
#if defined(__HIP_DEVICE_COMPILE__)
  return __builtin_amdgcn_rcpf(x);
#else
  return 1.0f/x;
#endif
}
__device__ __forceinline__ float tanh_fast(float x){
  float e = exp2f_fast(x * 2.885390081777927f);   // 2*log2(e)
  return 1.0f - 2.0f * rcpf_fast(1.0f + e);
}
__device__ __forceinline__ float sigmoid_fast(float x){
  return rcpf_fast(1.0f + exp2f_fast(x * -1.4426950408889634f));
}

#define SCALE_K2 2.885390081777927f   // 2*log2(e)

// ==== 128x128-tile GEMM helpers ==========================================
__device__ __forceinline__ void stage_t128(float* Ls, const float* g, int ldg){
  int tid = threadIdx.x;
  int r = tid >> 4, kq = (tid & 15) * 4;
  #pragma unroll
  for (int it = 0; it < 8; it++){
    int rr = r + 16*it;
    float4 v = *(const float4*)(g + (size_t)rr*ldg + kq);
    Ls[(kq+0)*132 + rr] = v.x;
    Ls[(kq+1)*132 + rr] = v.y;
    Ls[(kq+2)*132 + rr] = v.z;
    Ls[(kq+3)*132 + rr] = v.w;
  }
}
__device__ __forceinline__ void stage_d128(float* Ls, const float* g, int ldg){
  int tid = threadIdx.x;
  int k = tid >> 5, eq = (tid & 31) * 4;
  #pragma unroll
  for (int it = 0; it < 8; it++){
    int kk = k + 8*it;
    float4 v = *(const float4*)(g + (size_t)kk*ldg + eq);
    *(float4*)(Ls + kk*132 + eq) = v;
  }
}
__device__ __forceinline__ void rg_inner128(const float* Xs, const float* Ws,
                                            float (&acc)[8][8], int rg, int cg){
  #pragma unroll 2
  for (int k = 0; k < 64; k++){
    const float* xr = Xs + k*132;
    const float* wr = Ws + k*132;
    float4 x0 = *(const float4*)(xr + rg*4);
    float4 x1 = *(const float4*)(xr + 64 + rg*4);
    float4 w0 = *(const float4*)(wr + cg*4);
    float4 w1 = *(const float4*)(wr + 64 + cg*4);
    float xv[8] = {x0.x,x0.y,x0.z,x0.w, x1.x,x1.y,x1.z,x1.w};
    float wv[8] = {w0.x,w0.y,w0.z,w0.w, w1.x,w1.y,w1.z,w1.w};
    #pragma unroll
    for (int i=0;i<8;i++)
      #pragma unroll
      for (int j=0;j<8;j++)
        acc[i][j] = fmaf(xv[i], wv[j], acc[i][j]);
  }
}
#define ROW_OF(i, rg) ((rg)*4 + ((i)&3) + ((i)>>2)*64)
#define COL_OF(j, cg) ((cg)*4 + ((j)&3) + ((j)>>2)*64)

// ---------------- K1 ------------------------------------------------------
__global__ __launch_bounds__(256) void k1_hq_pp(
    const float* __restrict__ P,
    const float* __restrict__ wq_w, const float* __restrict__ wq_b,
    const float* __restrict__ wp_w, const float* __restrict__ wp_b,
    float* __restrict__ HQ, float* __restrict__ PP)
{
  __shared__ __align__(16) float Xs[64*132];
  __shared__ __align__(16) float Ws[64*132];
  int rt = blockIdx.x, ct = blockIdx.y;
  const float* W  = (ct < 2) ? wq_w : wp_w;
  const float* Bv = (ct < 2) ? wq_b : wp_b;
  float* O = (ct < 2) ? HQ : PP;
  int c0 = (ct & 1) * 128, r0 = rt * 128;
  int tid = threadIdx.x, rg = tid & 15, cg = tid >> 4;
  float acc[8][8];
  #pragma unroll
  for (int i=0;i<8;i++)
    #pragma unroll
    for (int j=0;j<8;j++) acc[i][j]=0.f;
  for (int kc = 0; kc < 4; kc++){
    __syncthreads();
    stage_t128(Xs, P + (size_t)r0*HH + kc*64, HH);
    stage_t128(Ws, W + (size_t)c0*HH + kc*64, HH);
    __syncthreads();
    rg_inner128(Xs, Ws, acc, rg, cg);
  }
  float bj[8];
  #pragma unroll
  for (int j=0;j<8;j++) bj[j] = Bv[c0 + COL_OF(j,cg)];
  #pragma unroll
  for (int i=0;i<8;i++){
    int r = r0 + ROW_OF(i,rg);
    #pragma unroll
    for (int j=0;j<8;j++)
      O[(size_t)r*HH + c0 + COL_OF(j,cg)] = SCALE_K2 * (acc[i][j] + bj[j]);
  }
}

// ---------------- K2 ------------------------------------------------------
__global__ __launch_bounds__(256) void k2_scores(
    const float* __restrict__ HQ, const float* __restrict__ PP,
    const float* __restrict__ ws_w, float* __restrict__ S)
{
  __shared__ float Hq_c[128*65];
  __shared__ float Pp_c[32*65];
  __shared__ float wsl[256];
  int tid = threadIdx.x;
  int b = blockIdx.y, t0 = blockIdx.x * 32;
  wsl[tid] = ws_w[tid];
  int tg = tid >> 6;
  int lg = tid & 63;
  for (int lc = 0; lc < 4; lc++){
    float acc[8][2];
    #pragma unroll
    for (int i=0;i<8;i++){ acc[i][0]=0.f; acc[i][1]=0.f; }
    for (int hc = 0; hc < 4; hc++){
      __syncthreads();
      {
        int r = tid >> 4, kq = (tid & 15) * 4;
        #pragma unroll
        for (int it=0; it<2; it++){
          int t = r + 16*it;
          float4 v = *(const float4*)(PP + ((size_t)b*LL + t0 + t)*HH + hc*64 + kq);
          float* d = Pp_c + t*65 + kq;
          d[0]=v.x; d[1]=v.y; d[2]=v.z; d[3]=v.w;
        }
      }
      {
        int r = tid >> 4, kq = (tid & 15) * 4;
        #pragma unroll
        for (int it=0; it<8; it++){
          int l = r + 16*it;
          float4 v = *(const float4*)(HQ + ((size_t)b*LL + lc*128 + l)*HH + hc*64 + kq);
          float* d = Hq_c + l*65 + kq;
          d[0]=v.x; d[1]=v.y; d[2]=v.z; d[3]=v.w;
        }
      }
      __syncthreads();
      #pragma unroll 2
      for (int h = 0; h < 64; h++){
        float w = wsl[hc*64 + h];
        float pp[8], hq[2];
        #pragma unroll
        for (int i=0;i<8;i++) pp[i] = Pp_c[(tg + 4*i)*65 + h];
        #pragma unroll
        for (int j=0;j<2;j++) hq[j] = Hq_c[(2*lg + j)*65 + h];
        #pragma unroll
        for (int i=0;i<8;i++)
          #pragma unroll
          for (int j=0;j<2;j++){
            float e = exp2f_fast(pp[i] + hq[j]);
            acc[i][j] = fmaf(w, rcpf_fast(1.0f + e), acc[i][j]);
          }
      }
    }
    #pragma unroll
    for (int i=0;i<8;i++)
      #pragma unroll
      for (int j=0;j<2;j++)
        S[((size_t)b*LL + t0 + tg + 4*i)*LL + lc*128 + 2*lg + j] = -2.0f*acc[i][j];
    __syncthreads();
  }
}

// ---------------- K3 ------------------------------------------------------
__global__ __launch_bounds__(256) void k3_softmax(float* __restrict__ S)
{
  int wave = threadIdx.x >> 6, lane = threadIdx.x & 63;
  size_t row = (size_t)blockIdx.x*4 + wave;
  float* p = S + row*LL;
  float v[8];
  #pragma unroll
  for (int i=0;i<8;i++) v[i] = p[lane + 64*i];
  float m = v[0];
  #pragma unroll
  for (int i=1;i<8;i++) m = fmaxf(m, v[i]);
  #pragma unroll
  for (int off=32; off>=1; off>>=1) m = fmaxf(m, __shfl_xor(m, off, 64));
  float s = 0.f;
  #pragma unroll
  for (int i=0;i<8;i++){ v[i] = exp2f_fast((v[i]-m)*1.4426950408889634f); s += v[i]; }
  #pragma unroll
  for (int off=32; off>=1; off>>=1) s += __shfl_xor(s, off, 64);
  float inv = 1.0f / s;
  #pragma unroll
  for (int i=0;i<8;i++) p[lane + 64*i] = v[i]*inv;
}

// ---------------- K4 ------------------------------------------------------
__global__ __launch_bounds__(256) void k4_context(
    const float* __restrict__ S, const float* __restrict__ P, float* __restrict__ C)
{
  __shared__ __align__(16) float As[64*132];
  __shared__ __align__(16) float Ps[64*132];
  int j0 = blockIdx.x * 128, t0 = blockIdx.y * 128, b = blockIdx.z;
  int tid = threadIdx.x, rg = tid & 15, cg = tid >> 4;
  float acc[8][8];
  #pragma unroll
  for (int i=0;i<8;i++)
    #pragma unroll
    for (int j=0;j<8;j++) acc[i][j]=0.f;
  for (int lc = 0; lc < 8; lc++){
    int l0 = lc*64;
    __syncthreads();
    stage_t128(As, S + ((size_t)b*LL + t0)*LL + l0, LL);
    stage_d128(Ps, P + ((size_t)b*LL + l0)*HH + j0, HH);
    __syncthreads();
    rg_inner128(As, Ps, acc, rg, cg);
  }
  #pragma unroll
  for (int i=0;i<8;i++){
    int t = t0 + ROW_OF(i,rg);
    #pragma unroll
    for (int j=0;j<8;j++)
      C[((size_t)b*LL + t)*HH + j0 + COL_OF(j,cg)] = acc[i][j];
  }
}

// ---------------- K5 ------------------------------------------------------
__global__ __launch_bounds__(256) void k5_gate(
    const float* __restrict__ P, const float* __restrict__ C,
    const float* __restrict__ wg_w, const float* __restrict__ wg_b,
    float* __restrict__ CG)
{
  __shared__ __align__(16) float Xs[64*132];
  __shared__ __align__(16) float Ws[64*132];
  int r0 = blockIdx.x*128, c0 = blockIdx.y*128;
  int tid = threadIdx.x, rg = tid & 15, cg = tid >> 4;
  float acc[8][8];
  #pragma unroll
  for (int i=0;i<8;i++)
    #pragma unroll
    for (int j=0;j<8;j++) acc[i][j]=0.f;
  for (int kc = 0; kc < 8; kc++){
    const float* Xsrc = (kc < 4) ? (P + (size_t)r0*HH + kc*64)
                                 : (C + (size_t)r0*HH + (kc-4)*64);
    __syncthreads();
    stage_t128(Xs, Xsrc, HH);
    stage_t128(Ws, wg_w + (size_t)c0*(2*HH) + kc*64, 2*HH);
    __syncthreads();
    rg_inner128(Xs, Ws, acc, rg, cg);
  }
  float bj[8];
  #pragma unroll
  for (int j=0;j<8;j++) bj[j] = wg_b[c0 + COL_OF(j,cg)];
  #pragma unroll
  for (int i=0;i<8;i++){
    int r = r0 + ROW_OF(i,rg);
    #pragma unroll
    for (int j=0;j<8;j++){
      int c = c0 + COL_OF(j,cg);
      float g = sigmoid_fast(acc[i][j] + bj[j]);
      CG[(size_t)r*HH + c] = g * C[(size_t)r*HH + c];
    }
  }
}

// ---------------- K6: GI = Cg @ Wih^T + bih (+ bhh for r/z cols only) -----
__global__ __launch_bounds__(256) void k6_gi(
    const float* __restrict__ CG,
    const float* __restrict__ Wih_l, const float* __restrict__ bih_l,
    const float* __restrict__ bhh_l,
    const float* __restrict__ Wih_r, const float* __restrict__ bih_r,
    const float* __restrict__ bhh_r,
    float* __restrict__ GIL, float* __restrict__ GIR)
{
  __shared__ __align__(16) float Xs[64*132];
  __shared__ __align__(16) float Ws[64*132];
  int rt = blockIdx.x, ct = blockIdx.y;
  int dir = (ct >= 6);
  const float* Wih = dir ? Wih_r : Wih_l;
  const float* bih = dir ? bih_r : bih_l;
  const float* bhh = dir ? bhh_r : bhh_l;
  float* GI = dir ? GIR : GIL;
  int c0 = (ct % 6) * 128, r0 = rt * 128;
  int tid = threadIdx.x, rg = tid & 15, cg = tid >> 4;
  float acc[8][8];
  #pragma unroll
  for (int i=0;i<8;i++)
    #pragma unroll
    for (int j=0;j<8;j++) acc[i][j]=0.f;
  for (int kc = 0; kc < 4; kc++){
    __syncthreads();
    stage_t128(Xs, CG + (size_t)r0*HH + kc*64, HH);
    stage_t128(Ws, Wih + (size_t)c0*HH + kc*64, HH);
    __syncthreads();
    rg_inner128(Xs, Ws, acc, rg, cg);
  }
  float bj[8];
  #pragma unroll
  for (int j=0;j<8;j++){
    int c = c0 + COL_OF(j,cg);
    // bhh_n is INSIDE the r-multiply (n = tanh(gin + r*(Whh h + bhh)_n)):
    // fold bhh only for the r/z blocks (cols < 512); k7 handles bhh_n.
    bj[j] = bih[c] + ((c < 512) ? bhh[c] : 0.f);
  }
  #pragma unroll
  for (int i=0;i<8;i++){
    int r = r0 + ROW_OF(i,rg);
    #pragma unroll
    for (int j=0;j<8;j++)
      GI[(size_t)r*768 + c0 + COL_OF(j,cg)] = acc[i][j] + bj[j];
  }
}

// ---------------- K7: MFMA GRU scans --------------------------------------
// 4 blocks: (dir, batch-half). 256 threads = 4 waves (1/SIMD, VGPR cap 512).
// Per step: C[768x16] = Whh * H^T via mfma_f32_16x16x32_f16; Whh resident in
// AGPRs as A-frags; lane (wv,q,m) owns units (wv*4+ut)*16+q*4+r4 of batch
// b0+m every step -> fp32 carry in hcar[16]. bhh_n loaded per lane and added
// to Cn inside the r-multiply. One barrier/step.

#define GI_STRIDE 772
#define HB_STRIDE 264

#define AS1F(p) ((const __attribute__((address_space(1))) float*)(p))
#define AS3F(p) ((__attribute__((address_space(3))) float*)(p))

__global__ __launch_bounds__(256) void k7_scan(
    const float* __restrict__ GIL, const float* __restrict__ GIR,
    const float* __restrict__ Whh_l, const float* __restrict__ Whh_r,
    const float* __restrict__ bhh_l, const float* __restrict__ bhh_r,
    float* __restrict__ out)
{
  int dir = blockIdx.x >> 1;
  int b0  = (blockIdx.x & 1) * 16;
  const float* GI  = dir ? GIR : GIL;
  const float* Whh = dir ? Whh_r : Whh_l;
  const float* bhh = dir ? bhh_r : bhh_l;

  int tid = threadIdx.x;
  int wv = tid >> 6, lane = tid & 63;
  int q = lane >> 4, m = lane & 15;   // A-row-quad / B-batch / D-col roles

  __shared__ __align__(16) float    gi_buf[2*16*GI_STRIDE];  // 98.8 KB
  __shared__ __align__(16) _Float16 Hb[2*16*HB_STRIDE];      // 16.9 KB

  // ---- load A fragments (Whh fp16), 12 tiles x 8 k-chunks = 384 regs ----
  f16x8 A[96];
  #pragma unroll
  for (int g = 0; g < 3; g++){
    #pragma unroll
    for (int ut = 0; ut < 4; ut++){
      int row = g*256 + (wv*4 + ut)*16 + m;
      const float* wr = Whh + (size_t)row*HH;
      #pragma unroll
      for (int kc = 0; kc < 8; kc++){
        int k = kc*32 + q*8;
        float4 lo = *(const float4*)(wr + k);
        float4 hi = *(const float4*)(wr + k + 4);
        f16x8 fa;
        fa[0]=(_Float16)lo.x; fa[1]=(_Float16)lo.y;
        fa[2]=(_Float16)lo.z; fa[3]=(_Float16)lo.w;
        fa[4]=(_Float16)hi.x; fa[5]=(_Float16)hi.y;
        fa[6]=(_Float16)hi.z; fa[7]=(_Float16)hi.w;
        A[(g*4+ut)*8 + kc] = fa;
      }
    }
  }

  // per-lane bhh_n for owned units: [ut][r4] at col 512 + u0
  float4 bhn[4];
  #pragma unroll
  for (int ut = 0; ut < 4; ut++){
    int u0 = (wv*4 + ut)*16 + q*4;
    bhn[ut] = *(const float4*)(bhh + 512 + u0);
  }

  for (int i = tid; i < 2*16*HB_STRIDE; i += 256) Hb[i] = (_Float16)0.f;

  float hcar[16];                      // fp32 h carry: [ut][r4], batch b0+m
  #pragma unroll
  for (int i = 0; i < 16; i++) hcar[i] = 0.f;

  // stage gi for step 0 into buffer 0
  {
    int t0 = dir ? (LL-1) : 0;
    #pragma unroll
    for (int bt2 = 0; bt2 < 4; bt2++){
      int bt = 4*wv + bt2;
      const float* src = GI + ((size_t)(b0+bt)*LL + t0)*768 + lane*4;
      #pragma unroll
      for (int c = 0; c < 3; c++)
        __builtin_amdgcn_global_load_lds(AS1F(src + c*256),
            AS3F(&gi_buf[bt*GI_STRIDE + c*256]), 16, 0, 0);
    }
  }
  __syncthreads();

  for (int s = 0; s < LL; s++){
    int buf = s & 1, nbuf = buf ^ 1;
    int t = dir ? (LL-1-s) : s;

    // prefetch gi for s+1 into the other buffer (drained by the barrier)
    if (s + 1 < LL){
      int tn = dir ? (LL-2-s) : (s+1);
      #pragma unroll
      for (int bt2 = 0; bt2 < 4; bt2++){
        int bt = 4*wv + bt2;
        const float* src = GI + ((size_t)(b0+bt)*LL + tn)*768 + lane*4;
        #pragma unroll
        for (int c = 0; c < 3; c++)
          __builtin_amdgcn_global_load_lds(AS1F(src + c*256),
              AS3F(&gi_buf[nbuf*16*GI_STRIDE + bt*GI_STRIDE + c*256]), 16, 0, 0);
      }
    }

    // ---- MFMA: C[tile] += A[tile,kc] * B[kc]  (B = h fragments) ----
    f32x4 acc[12];
    #pragma unroll
    for (int i = 0; i < 12; i++){ f32x4 z = {0.f,0.f,0.f,0.f}; acc[i] = z; }
    const _Float16* hb = &Hb[buf*16*HB_STRIDE];
    #pragma unroll
    for (int kc = 0; kc < 8; kc++){
      f16x8 bfr = *(const f16x8*)(hb + m*HB_STRIDE + kc*32 + q*8);
      #pragma unroll
      for (int t12 = 0; t12 < 12; t12++)
        acc[t12] = __builtin_amdgcn_mfma_f32_16x16x32_f16(A[t12*8 + kc], bfr, acc[t12], 0, 0, 0);
    }

    // ---- gates, fp32 carry in registers; bhh_n inside the r-multiply ----
    const float* gib = &gi_buf[buf*16*GI_STRIDE + m*GI_STRIDE];
    #pragma unroll
    for (int ut = 0; ut < 4; ut++){
      int u0 = (wv*4 + ut)*16 + q*4;
      float4 gR = *(const float4*)(gib + u0);
      float4 gZ = *(const float4*)(gib + 256 + u0);
      float4 gN = *(const float4*)(gib + 512 + u0);
      f32x4 Cr = acc[0*4+ut], Cz = acc[1*4+ut], Cn = acc[2*4+ut];
      float gRv[4] = {gR.x, gR.y, gR.z, gR.w};
      float gZv[4] = {gZ.x, gZ.y, gZ.z, gZ.w};
      float gNv[4] = {gN.x, gN.y, gN.z, gN.w};
      float bnv[4] = {bhn[ut].x, bhn[ut].y, bhn[ut].z, bhn[ut].w};
      float hv[4];
      #pragma unroll
      for (int r4 = 0; r4 < 4; r4++){
        float rr = sigmoid_fast(gRv[r4] + Cr[r4]);
        float zz = sigmoid_fast(gZv[r4] + Cz[r4]);
        float nn = tanh_fast(gNv[r4] + rr*(Cn[r4] + bnv[r4]));
        float hp = hcar[ut*4 + r4];
        float hn = zz*(hp - nn) + nn;
        hcar[ut*4 + r4] = hn;
        hv[r4] = hn;
      }
      *(float4*)&out[((size_t)(b0+m)*LL + t)*(2*HH) + dir*HH + u0] =
          make_float4(hv[0], hv[1], hv[2], hv[3]);
      f16x4 hh;
      hh[0]=(_Float16)hv[0]; hh[1]=(_Float16)hv[1];
      hh[2]=(_Float16)hv[2]; hh[3]=(_Float16)hv[3];
      *(f16x4*)(&Hb[nbuf*16*HB_STRIDE + m*HB_STRIDE + u0]) = hh;
    }
    __syncthreads();   // drains gi prefetch + publishes Hb[nbuf]
  }
}

extern "C" void kernel_launch(void* const* d_in, const int* in_sizes, int n_in,
                              void* d_out, int out_size, void* d_ws, size_t ws_size,
                              hipStream_t stream)
{
  const float* P    = (const float*)d_in[0];
  const float* wq_w = (const float*)d_in[1];
  const float* wq_b = (const float*)d_in[2];
  const float* wp_w = (const float*)d_in[3];
  const float* wp_b = (const float*)d_in[4];
  const float* ws_w = (const float*)d_in[5];
  // d_in[6] = ws_b: softmax-invariant, unused
  const float* wg_w = (const float*)d_in[7];
  const float* wg_b = (const float*)d_in[8];
  const float* Wih_l= (const float*)d_in[9];
  const float* Whh_l= (const float*)d_in[10];
  const float* bih_l= (const float*)d_in[11];
  const float* bhh_l= (const float*)d_in[12];
  const float* Wih_r= (const float*)d_in[13];
  const float* Whh_r= (const float*)d_in[14];
  const float* bih_r= (const float*)d_in[15];
  const float* bhh_r= (const float*)d_in[16];

  float* ws  = (float*)d_ws;
  float* HQ  = ws;                    //  4,194,304
  float* PP  = ws + 4194304;          //  4,194,304
  float* S   = ws + 8388608;          //  8,388,608
  float* C   = ws + 16777216;         //  4,194,304
  float* CG  = ws + 20971520;         //  4,194,304
  float* GIR = ws + 25165824;         // 12,582,912
  float* GIL = ws;                    // 12,582,912 (aliases HQ/PP/S-front; dead by k6)
  float* out = (float*)d_out;

  k1_hq_pp  <<<dim3(128, 4),    256, 0, stream>>>(P, wq_w, wq_b, wp_w, wp_b, HQ, PP);
  k2_scores <<<dim3(16, 32),    256, 0, stream>>>(HQ, PP, ws_w, S);
  k3_softmax<<<4096,            256, 0, stream>>>(S);
  k4_context<<<dim3(2, 4, 32),  256, 0, stream>>>(S, P, C);
  k5_gate   <<<dim3(128, 2),    256, 0, stream>>>(P, C, wg_w, wg_b, CG);
  k6_gi     <<<dim3(128, 12),   256, 0, stream>>>(CG, Wih_l, bih_l, bhh_l,
                                                  Wih_r, bih_r, bhh_r, GIL, GIR);
  k7_scan   <<<4,               256, 0, stream>>>(GIL, GIR, Whh_l, Whh_r,
                                                  bhh_l, bhh_r, out);
}

// Round 7
// 1890.882 us; speedup vs baseline: 1.2403x; 1.2403x over previous
//
#include <hip/hip_runtime.h>
#include <cstdint>

// SelfMatchingLayer: B=32, L=512, H=256, fp32.
// R7: k7 at 256thr was 1 wave/SIMD -> zero co-scheduling; step = 6516 cyc
// vs 1863-cyc MFMA floor (384 mfma-inst/CU-step x 4.85 cyc). Rebuild k7 at
// 512 thr (2 waves/SIMD, 256 unified regs/wave): wave owns 2 unit-groups
// (48 MFMA, A=192 AGPRs), gates per-group (acc live=12), 48 trans/lane.
// Cross-wave overlap (m114) hides gates under MFMA. k1-k6 unchanged.

#define LL 512
#define HH 256

typedef _Float16 f16x8 __attribute__((ext_vector_type(8)));
typedef _Float16 f16x4 __attribute__((ext_vector_type(4)));
typedef float    f32x4 __attribute__((ext_vector_type(4)));

__device__ __forceinline__ float exp2f_fast(float x){
#if defined(__HIP_DEVICE_COMPILE__)
  return __builtin_amdgcn_exp2f(x);
#else
  return exp2f(x);
#endif
}
__device__ __forceinline__ float rcpf_fast(float x){
#if defined(__HIP_DEVICE_COMPILE__)
  return __builtin_amdgcn_rcpf(x);
#else
  return 1.0f/x;
#endif
}
__device__ __forceinline__ float tanh_fast(float x){
  float e = exp2f_fast(x * 2.885390081777927f);   // 2*log2(e)
  return 1.0f - 2.0f * rcpf_fast(1.0f + e);
}
__device__ __forceinline__ float sigmoid_fast(float x){
  return rcpf_fast(1.0f + exp2f_fast(x * -1.4426950408889634f));
}

#define SCALE_K2 2.885390081777927f   // 2*log2(e)

// ==== 128x128-tile GEMM helpers ==========================================
__device__ __forceinline__ void stage_t128(float* Ls, const float* g, int ldg){
  int tid = threadIdx.x;
  int r = tid >> 4, kq = (tid & 15) * 4;
  #pragma unroll
  for (int it = 0; it < 8; it++){
    int rr = r + 16*it;
    float4 v = *(const float4*)(g + (size_t)rr*ldg + kq);
    Ls[(kq+0)*132 + rr] = v.x;
    Ls[(kq+1)*132 + rr] = v.y;
    Ls[(kq+2)*132 + rr] = v.z;
    Ls[(kq+3)*132 + rr] = v.w;
  }
}
__device__ __forceinline__ void stage_d128(float* Ls, const float* g, int ldg){
  int tid = threadIdx.x;
  int k = tid >> 5, eq = (tid & 31) * 4;
  #pragma unroll
  for (int it = 0; it < 8; it++){
    int kk = k + 8*it;
    float4 v = *(const float4*)(g + (size_t)kk*ldg + eq);
    *(float4*)(Ls + kk*132 + eq) = v;
  }
}
__device__ __forceinline__ void rg_inner128(const float* Xs, const float* Ws,
                                            float (&acc)[8][8], int rg, int cg){
  #pragma unroll 2
  for (int k = 0; k < 64; k++){
    const float* xr = Xs + k*132;
    const float* wr = Ws + k*132;
    float4 x0 = *(const float4*)(xr + rg*4);
    float4 x1 = *(const float4*)(xr + 64 + rg*4);
    float4 w0 = *(const float4*)(wr + cg*4);
    float4 w1 = *(const float4*)(wr + 64 + cg*4);
    float xv[8] = {x0.x,x0.y,x0.z,x0.w, x1.x,x1.y,x1.z,x1.w};
    float wv[8] = {w0.x,w0.y,w0.z,w0.w, w1.x,w1.y,w1.z,w1.w};
    #pragma unroll
    for (int i=0;i<8;i++)
      #pragma unroll
      for (int j=0;j<8;j++)
        acc[i][j] = fmaf(xv[i], wv[j], acc[i][j]);
  }
}
#define ROW_OF(i, rg) ((rg)*4 + ((i)&3) + ((i)>>2)*64)
#define COL_OF(j, cg) ((cg)*4 + ((j)&3) + ((j)>>2)*64)

// ---------------- K1 ------------------------------------------------------
__global__ __launch_bounds__(256) void k1_hq_pp(
    const float* __restrict__ P,
    const float* __restrict__ wq_w, const float* __restrict__ wq_b,
    const float* __restrict__ wp_w, const float* __restrict__ wp_b,
    float* __restrict__ HQ, float* __restrict__ PP)
{
  __shared__ __align__(16) float Xs[64*132];
  __shared__ __align__(16) float Ws[64*132];
  int rt = blockIdx.x, ct = blockIdx.y;
  const float* W  = (ct < 2) ? wq_w : wp_w;
  const float* Bv = (ct < 2) ? wq_b : wp_b;
  float* O = (ct < 2) ? HQ : PP;
  int c0 = (ct & 1) * 128, r0 = rt * 128;
  int tid = threadIdx.x, rg = tid & 15, cg = tid >> 4;
  float acc[8][8];
  #pragma unroll
  for (int i=0;i<8;i++)
    #pragma unroll
    for (int j=0;j<8;j++) acc[i][j]=0.f;
  for (int kc = 0; kc < 4; kc++){
    __syncthreads();
    stage_t128(Xs, P + (size_t)r0*HH + kc*64, HH);
    stage_t128(Ws, W + (size_t)c0*HH + kc*64, HH);
    __syncthreads();
    rg_inner128(Xs, Ws, acc, rg, cg);
  }
  float bj[8];
  #pragma unroll
  for (int j=0;j<8;j++) bj[j] = Bv[c0 + COL_OF(j,cg)];
  #pragma unroll
  for (int i=0;i<8;i++){
    int r = r0 + ROW_OF(i,rg);
    #pragma unroll
    for (int j=0;j<8;j++)
      O[(size_t)r*HH + c0 + COL_OF(j,cg)] = SCALE_K2 * (acc[i][j] + bj[j]);
  }
}

// ---------------- K2 ------------------------------------------------------
__global__ __launch_bounds__(256) void k2_scores(
    const float* __restrict__ HQ, const float* __restrict__ PP,
    const float* __restrict__ ws_w, float* __restrict__ S)
{
  __shared__ float Hq_c[128*65];
  __shared__ float Pp_c[32*65];
  __shared__ float wsl[256];
  int tid = threadIdx.x;
  int b = blockIdx.y, t0 = blockIdx.x * 32;
  wsl[tid] = ws_w[tid];
  int tg = tid >> 6;
  int lg = tid & 63;
  for (int lc = 0; lc < 4; lc++){
    float acc[8][2];
    #pragma unroll
    for (int i=0;i<8;i++){ acc[i][0]=0.f; acc[i][1]=0.f; }
    for (int hc = 0; hc < 4; hc++){
      __syncthreads();
      {
        int r = tid >> 4, kq = (tid & 15) * 4;
        #pragma unroll
        for (int it=0; it<2; it++){
          int t = r + 16*it;
          float4 v = *(const float4*)(PP + ((size_t)b*LL + t0 + t)*HH + hc*64 + kq);
          float* d = Pp_c + t*65 + kq;
          d[0]=v.x; d[1]=v.y; d[2]=v.z; d[3]=v.w;
        }
      }
      {
        int r = tid >> 4, kq = (tid & 15) * 4;
        #pragma unroll
        for (int it=0; it<8; it++){
          int l = r + 16*it;
          float4 v = *(const float4*)(HQ + ((size_t)b*LL + lc*128 + l)*HH + hc*64 + kq);
          float* d = Hq_c + l*65 + kq;
          d[0]=v.x; d[1]=v.y; d[2]=v.z; d[3]=v.w;
        }
      }
      __syncthreads();
      #pragma unroll 2
      for (int h = 0; h < 64; h++){
        float w = wsl[hc*64 + h];
        float pp[8], hq[2];
        #pragma unroll
        for (int i=0;i<8;i++) pp[i] = Pp_c[(tg + 4*i)*65 + h];
        #pragma unroll
        for (int j=0;j<2;j++) hq[j] = Hq_c[(2*lg + j)*65 + h];
        #pragma unroll
        for (int i=0;i<8;i++)
          #pragma unroll
          for (int j=0;j<2;j++){
            float e = exp2f_fast(pp[i] + hq[j]);
            acc[i][j] = fmaf(w, rcpf_fast(1.0f + e), acc[i][j]);
          }
      }
    }
    #pragma unroll
    for (int i=0;i<8;i++)
      #pragma unroll
      for (int j=0;j<2;j++)
        S[((size_t)b*LL + t0 + tg + 4*i)*LL + lc*128 + 2*lg + j] = -2.0f*acc[i][j];
    __syncthreads();
  }
}

// ---------------- K3 ------------------------------------------------------
__global__ __launch_bounds__(256) void k3_softmax(float* __restrict__ S)
{
  int wave = threadIdx.x >> 6, lane = threadIdx.x & 63;
  size_t row = (size_t)blockIdx.x*4 + wave;
  float* p = S + row*LL;
  float v[8];
  #pragma unroll
  for (int i=0;i<8;i++) v[i] = p[lane + 64*i];
  float m = v[0];
  #pragma unroll
  for (int i=1;i<8;i++) m = fmaxf(m, v[i]);
  #pragma unroll
  for (int off=32; off>=1; off>>=1) m = fmaxf(m, __shfl_xor(m, off, 64));
  float s = 0.f;
  #pragma unroll
  for (int i=0;i<8;i++){ v[i] = exp2f_fast((v[i]-m)*1.4426950408889634f); s += v[i]; }
  #pragma unroll
  for (int off=32; off>=1; off>>=1) s += __shfl_xor(s, off, 64);
  float inv = 1.0f / s;
  #pragma unroll
  for (int i=0;i<8;i++) p[lane + 64*i] = v[i]*inv;
}

// ---------------- K4 ------------------------------------------------------
__global__ __launch_bounds__(256) void k4_context(
    const float* __restrict__ S, const float* __restrict__ P, float* __restrict__ C)
{
  __shared__ __align__(16) float As[64*132];
  __shared__ __align__(16) float Ps[64*132];
  int j0 = blockIdx.x * 128, t0 = blockIdx.y * 128, b = blockIdx.z;
  int tid = threadIdx.x, rg = tid & 15, cg = tid >> 4;
  float acc[8][8];
  #pragma unroll
  for (int i=0;i<8;i++)
    #pragma unroll
    for (int j=0;j<8;j++) acc[i][j]=0.f;
  for (int lc = 0; lc < 8; lc++){
    int l0 = lc*64;
    __syncthreads();
    stage_t128(As, S + ((size_t)b*LL + t0)*LL + l0, LL);
    stage_d128(Ps, P + ((size_t)b*LL + l0)*HH + j0, HH);
    __syncthreads();
    rg_inner128(As, Ps, acc, rg, cg);
  }
  #pragma unroll
  for (int i=0;i<8;i++){
    int t = t0 + ROW_OF(i,rg);
    #pragma unroll
    for (int j=0;j<8;j++)
      C[((size_t)b*LL + t)*HH + j0 + COL_OF(j,cg)] = acc[i][j];
  }
}

// ---------------- K5 ------------------------------------------------------
__global__ __launch_bounds__(256) void k5_gate(
    const float* __restrict__ P, const float* __restrict__ C,
    const float* __restrict__ wg_w, const float* __restrict__ wg_b,
    float* __restrict__ CG)
{
  __shared__ __align__(16) float Xs[64*132];
  __shared__ __align__(16) float Ws[64*132];
  int r0 = blockIdx.x*128, c0 = blockIdx.y*128;
  int tid = threadIdx.x, rg = tid & 15, cg = tid >> 4;
  float acc[8][8];
  #pragma unroll
  for (int i=0;i<8;i++)
    #pragma unroll
    for (int j=0;j<8;j++) acc[i][j]=0.f;
  for (int kc = 0; kc < 8; kc++){
    const float* Xsrc = (kc < 4) ? (P + (size_t)r0*HH + kc*64)
                                 : (C + (size_t)r0*HH + (kc-4)*64);
    __syncthreads();
    stage_t128(Xs, Xsrc, HH);
    stage_t128(Ws, wg_w + (size_t)c0*(2*HH) + kc*64, 2*HH);
    __syncthreads();
    rg_inner128(Xs, Ws, acc, rg, cg);
  }
  float bj[8];
  #pragma unroll
  for (int j=0;j<8;j++) bj[j] = wg_b[c0 + COL_OF(j,cg)];
  #pragma unroll
  for (int i=0;i<8;i++){
    int r = r0 + ROW_OF(i,rg);
    #pragma unroll
    for (int j=0;j<8;j++){
      int c = c0 + COL_OF(j,cg);
      float g = sigmoid_fast(acc[i][j] + bj[j]);
      CG[(size_t)r*HH + c] = g * C[(size_t)r*HH + c];
    }
  }
}

// ---------------- K6: GI = Cg @ Wih^T + bih (+ bhh for r/z cols only) -----
__global__ __launch_bounds__(256) void k6_gi(
    const float* __restrict__ CG,
    const float* __restrict__ Wih_l, const float* __restrict__ bih_l,
    const float* __restrict__ bhh_l,
    const float* __restrict__ Wih_r, const float* __restrict__ bih_r,
    const float* __restrict__ bhh_r,
    float* __restrict__ GIL, float* __restrict__ GIR)
{
  __shared__ __align__(16) float Xs[64*132];
  __shared__ __align__(16) float Ws[64*132];
  int rt = blockIdx.x, ct = blockIdx.y;
  int dir = (ct >= 6);
  const float* Wih = dir ? Wih_r : Wih_l;
  const float* bih = dir ? bih_r : bih_l;
  const float* bhh = dir ? bhh_r : bhh_l;
  float* GI = dir ? GIR : GIL;
  int c0 = (ct % 6) * 128, r0 = rt * 128;
  int tid = threadIdx.x, rg = tid & 15, cg = tid >> 4;
  float acc[8][8];
  #pragma unroll
  for (int i=0;i<8;i++)
    #pragma unroll
    for (int j=0;j<8;j++) acc[i][j]=0.f;
  for (int kc = 0; kc < 4; kc++){
    __syncthreads();
    stage_t128(Xs, CG + (size_t)r0*HH + kc*64, HH);
    stage_t128(Ws, Wih + (size_t)c0*HH + kc*64, HH);
    __syncthreads();
    rg_inner128(Xs, Ws, acc, rg, cg);
  }
  float bj[8];
  #pragma unroll
  for (int j=0;j<8;j++){
    int c = c0 + COL_OF(j,cg);
    // bhh_n is INSIDE the r-multiply: fold bhh only for r/z (cols < 512).
    bj[j] = bih[c] + ((c < 512) ? bhh[c] : 0.f);
  }
  #pragma unroll
  for (int i=0;i<8;i++){
    int r = r0 + ROW_OF(i,rg);
    #pragma unroll
    for (int j=0;j<8;j++)
      GI[(size_t)r*768 + c0 + COL_OF(j,cg)] = acc[i][j] + bj[j];
  }
}

// ---------------- K7: MFMA GRU scans, 512 thr / 2 waves per SIMD ----------
// 4 blocks (dir, batch-half) x 8 waves. Wave w owns unit-groups {2w, 2w+1};
// per group: 3 tiles (r,z,n) x 8 kc MFMAs, acc live = 12 regs; A = 192 regs
// (per-wave AGPR). Lane (q,m): batch b0+m, units ug*16+q*4+r4; fp32 carry in
// hcar[8]. gi double-buffered via global_load_lds (wave-uniform LDS base);
// one barrier/step. Per-wave regs ~= 192 A + ~55 V < 256 (2 waves/SIMD).

#define GI_STRIDE 772
#define HB_STRIDE 264

#define AS1F(p) ((const __attribute__((address_space(1))) float*)(p))
#define AS3F(p) ((__attribute__((address_space(3))) float*)(p))

__global__ __launch_bounds__(512, 2) void k7_scan(
    const float* __restrict__ GIL, const float* __restrict__ GIR,
    const float* __restrict__ Whh_l, const float* __restrict__ Whh_r,
    const float* __restrict__ bhh_l, const float* __restrict__ bhh_r,
    float* __restrict__ out)
{
  int dir = blockIdx.x >> 1;
  int b0  = (blockIdx.x & 1) * 16;
  const float* GI  = dir ? GIR : GIL;
  const float* Whh = dir ? Whh_r : Whh_l;
  const float* bhh = dir ? bhh_r : bhh_l;

  int tid = threadIdx.x;
  int w = tid >> 6, lane = tid & 63;
  int q = lane >> 4, m = lane & 15;

  __shared__ __align__(16) float    gi_buf[2*16*GI_STRIDE];  // 98.8 KB
  __shared__ __align__(16) _Float16 Hb[2*16*HB_STRIDE];      // 16.9 KB

  // ---- A fragments: 2 groups x 3 gate-tiles x 8 kc = 48 x f16x8 (192 r) --
  f16x8 A[48];
  #pragma unroll
  for (int j = 0; j < 2; j++){
    int ug = 2*w + j;
    #pragma unroll
    for (int g3 = 0; g3 < 3; g3++){
      int row = g3*256 + ug*16 + m;
      const float* wr = Whh + (size_t)row*HH;
      #pragma unroll
      for (int kc = 0; kc < 8; kc++){
        int k = kc*32 + q*8;
        float4 lo = *(const float4*)(wr + k);
        float4 hi = *(const float4*)(wr + k + 4);
        f16x8 fa;
        fa[0]=(_Float16)lo.x; fa[1]=(_Float16)lo.y;
        fa[2]=(_Float16)lo.z; fa[3]=(_Float16)lo.w;
        fa[4]=(_Float16)hi.x; fa[5]=(_Float16)hi.y;
        fa[6]=(_Float16)hi.z; fa[7]=(_Float16)hi.w;
        A[(j*3 + g3)*8 + kc] = fa;
      }
    }
  }

  float4 bhn[2];
  #pragma unroll
  for (int j = 0; j < 2; j++){
    int u0 = (2*w + j)*16 + q*4;
    bhn[j] = *(const float4*)(bhh + 512 + u0);
  }

  for (int i = tid; i < 2*16*HB_STRIDE; i += 512) Hb[i] = (_Float16)0.f;

  float hcar[8];
  #pragma unroll
  for (int i = 0; i < 8; i++) hcar[i] = 0.f;

  // stage gi for step 0 into buffer 0 (wave handles batches 2w, 2w+1)
  {
    int t0 = dir ? (LL-1) : 0;
    #pragma unroll
    for (int j2 = 0; j2 < 2; j2++){
      int bt = 2*w + j2;
      const float* src = GI + ((size_t)(b0+bt)*LL + t0)*768 + lane*4;
      #pragma unroll
      for (int c = 0; c < 3; c++)
        __builtin_amdgcn_global_load_lds(AS1F(src + c*256),
            AS3F(&gi_buf[bt*GI_STRIDE + c*256]), 16, 0, 0);
    }
  }
  __syncthreads();

  for (int s = 0; s < LL; s++){
    int buf = s & 1, nbuf = buf ^ 1;
    int t = dir ? (LL-1-s) : s;

    // prefetch gi for s+1 into the other buffer (drained by end barrier)
    if (s + 1 < LL){
      int tn = dir ? (LL-2-s) : (s+1);
      #pragma unroll
      for (int j2 = 0; j2 < 2; j2++){
        int bt = 2*w + j2;
        const float* src = GI + ((size_t)(b0+bt)*LL + tn)*768 + lane*4;
        #pragma unroll
        for (int c = 0; c < 3; c++)
          __builtin_amdgcn_global_load_lds(AS1F(src + c*256),
              AS3F(&gi_buf[nbuf*16*GI_STRIDE + bt*GI_STRIDE + c*256]), 16, 0, 0);
      }
    }

    const _Float16* hb  = &Hb[buf*16*HB_STRIDE];
    const float*    gib = &gi_buf[buf*16*GI_STRIDE + m*GI_STRIDE];

    #pragma unroll
    for (int j = 0; j < 2; j++){
      int ug = 2*w + j;
      int u0 = ug*16 + q*4;
      // MFMA: r,z,n tiles of this group over K=256
      f32x4 aR = {0.f,0.f,0.f,0.f}, aZ = aR, aN = aR;
      #pragma unroll
      for (int kc = 0; kc < 8; kc++){
        f16x8 bfr = *(const f16x8*)(hb + m*HB_STRIDE + kc*32 + q*8);
        aR = __builtin_amdgcn_mfma_f32_16x16x32_f16(A[(j*3+0)*8+kc], bfr, aR, 0,0,0);
        aZ = __builtin_amdgcn_mfma_f32_16x16x32_f16(A[(j*3+1)*8+kc], bfr, aZ, 0,0,0);
        aN = __builtin_amdgcn_mfma_f32_16x16x32_f16(A[(j*3+2)*8+kc], bfr, aN, 0,0,0);
      }
      // gates
      float4 gR = *(const float4*)(gib + u0);
      float4 gZ = *(const float4*)(gib + 256 + u0);
      float4 gN = *(const float4*)(gib + 512 + u0);
      float gRv[4] = {gR.x, gR.y, gR.z, gR.w};
      float gZv[4] = {gZ.x, gZ.y, gZ.z, gZ.w};
      float gNv[4] = {gN.x, gN.y, gN.z, gN.w};
      float bnv[4] = {bhn[j].x, bhn[j].y, bhn[j].z, bhn[j].w};
      float hv[4];
      #pragma unroll
      for (int r4 = 0; r4 < 4; r4++){
        float rr = sigmoid_fast(gRv[r4] + aR[r4]);
        float zz = sigmoid_fast(gZv[r4] + aZ[r4]);
        float nn = tanh_fast(gNv[r4] + rr*(aN[r4] + bnv[r4]));
        float hp = hcar[j*4 + r4];
        float hn = zz*(hp - nn) + nn;
        hcar[j*4 + r4] = hn;
        hv[r4] = hn;
      }
      *(float4*)&out[((size_t)(b0+m)*LL + t)*(2*HH) + dir*HH + u0] =
          make_float4(hv[0], hv[1], hv[2], hv[3]);
      f16x4 hh;
      hh[0]=(_Float16)hv[0]; hh[1]=(_Float16)hv[1];
      hh[2]=(_Float16)hv[2]; hh[3]=(_Float16)hv[3];
      *(f16x4*)(&Hb[nbuf*16*HB_STRIDE + m*HB_STRIDE + u0]) = hh;
    }
    __syncthreads();   // drains gi prefetch + publishes Hb[nbuf]
  }
}

extern "C" void kernel_launch(void* const* d_in, const int* in_sizes, int n_in,
                              void* d_out, int out_size, void* d_ws, size_t ws_size,
                              hipStream_t stream)
{
  const float* P    = (const float*)d_in[0];
  const float* wq_w = (const float*)d_in[1];
  const float* wq_b = (const float*)d_in[2];
  const float* wp_w = (const float*)d_in[3];
  const float* wp_b = (const float*)d_in[4];
  const float* ws_w = (const float*)d_in[5];
  // d_in[6] = ws_b: softmax-invariant, unused
  const float* wg_w = (const float*)d_in[7];
  const float* wg_b = (const float*)d_in[8];
  const float* Wih_l= (const float*)d_in[9];
  const float* Whh_l= (const float*)d_in[10];
  const float* bih_l= (const float*)d_in[11];
  const float* bhh_l= (const float*)d_in[12];
  const float* Wih_r= (const float*)d_in[13];
  const float* Whh_r= (const float*)d_in[14];
  const float* bih_r= (const float*)d_in[15];
  const float* bhh_r= (const float*)d_in[16];

  float* ws  = (float*)d_ws;
  float* HQ  = ws;                    //  4,194,304
  float* PP  = ws + 4194304;          //  4,194,304
  float* S   = ws + 8388608;          //  8,388,608
  float* C   = ws + 16777216;         //  4,194,304
  float* CG  = ws + 20971520;         //  4,194,304
  float* GIR = ws + 25165824;         // 12,582,912
  float* GIL = ws;                    // 12,582,912 (aliases HQ/PP/S-front; dead by k6)
  float* out = (float*)d_out;

  k1_hq_pp  <<<dim3(128, 4),    256, 0, stream>>>(P, wq_w, wq_b, wp_w, wp_b, HQ, PP);
  k2_scores <<<dim3(16, 32),    256, 0, stream>>>(HQ, PP, ws_w, S);
  k3_softmax<<<4096,            256, 0, stream>>>(S);
  k4_context<<<dim3(2, 4, 32),  256, 0, stream>>>(S, P, C);
  k5_gate   <<<dim3(128, 2),    256, 0, stream>>>(P, C, wg_w, wg_b, CG);
  k6_gi     <<<dim3(128, 12),   256, 0, stream>>>(CG, Wih_l, bih_l, bhh_l,
                                                  Wih_r, bih_r, bhh_r, GIL, GIR);
  k7_scan   <<<4,               512, 0, stream>>>(GIL, GIR, Whh_l, Whh_r,
                                                  bhh_l, bhh_r, out);
}